// Round 5
// baseline (583.956 us; speedup 1.0000x reference)
//
#include <hip/hip_runtime.h>

#define B 16
#define C 512
#define HW 4096
#define KK 49

// ---------------- workspace layout (floats), with lifetime overlaps ----------
// kwT    [512][64]        0         (32768)
// c0wT   [512][512]       32768     (262144)
// c1wT   [512][512]       294912    (262144)
// stats  [B][49][2]       557056    (1568)
// keyraw [B][49][4096]    558624    (3211264)   dead after k2b
//   fsum [B][512][49]     558624    (401408)    written by k3_sum (after k2b)
//   t0   [B][512][49]     960032
//   g    [B][512][49]     1361440
//   t1   [B][512][49]     1762848
// ksmT   [B][4096][64]    3769888   (4194304)   dead after k3
// kpart  [4][B][49][4096] 7964192   (12845056)  dead after k2a_fused
//   fpart[32][B][512][49] 7964192   (12845056)  written by k3 (after k2a)
// total 20,809,248 floats = 83.2 MB
#define OFF_KWT    0
#define OFF_C0WT   32768
#define OFF_C1WT   294912
#define OFF_STATS  557056
#define OFF_KEYRAW 558624
#define OFF_FSUM   558624
#define OFF_T0     960032
#define OFF_G      1361440
#define OFF_T1     1762848
#define OFF_KSMT   3769888
#define OFF_KPART  7964192
#define OFF_FPART  7964192
#define KP_SLICE   3211264   // B*KK*HW

// k0: transpose the three weight matrices (tiny, one-shot)
__global__ __launch_bounds__(256) void k0_transpose(
    const float* __restrict__ K_w, const float* __restrict__ c0w,
    const float* __restrict__ c1w, float* __restrict__ kwT,
    float* __restrict__ c0wT, float* __restrict__ c1wT) {
  int i = blockIdx.x * 256 + threadIdx.x;
  if (i < 512 * KK) {
    int cc = i / KK, oo = i % KK;
    kwT[cc * 64 + oo] = K_w[oo * 512 + cc];
  }
  if (i < 512 * 512) {
    int cc = i >> 9, oo = i & 511;
    c0wT[i] = c0w[oo * 512 + cc];
    c1wT[i] = c1w[oo * 512 + cc];
  }
}

// k1: kpart[cs][b][o][n] = sum_{c in cs-chunk} K_w[o][c] * x[b][c][n]
// o-split 2 (acc[25], o=24 duplicated benignly) + explicit 8-deep prefetch.
// 2048 blocks, <=64 VGPR -> 8 waves/SIMD.
__global__ __launch_bounds__(256, 8) void k1_key(
    const float* __restrict__ x, const float* __restrict__ kwT,
    float* __restrict__ kpart) {
  int b = blockIdx.y;
  int cs = blockIdx.z >> 1;   // 0..3, 128 channels each
  int ob = (blockIdx.z & 1) * 24;  // o-half base: 0..24 or 24..48
  int n = blockIdx.x * 256 + threadIdx.x;
  const float* xp = x + ((size_t)(b * C) + cs * 128) * HW + n;
  float acc[25];
#pragma unroll
  for (int o = 0; o < 25; o++) acc[o] = 0.f;
  float xc[8], xn[8];
#pragma unroll
  for (int u = 0; u < 8; u++) xc[u] = xp[(size_t)u * HW];
  for (int c0 = 0; c0 < 128; c0 += 8) {
    if (c0 + 8 < 128) {
#pragma unroll
      for (int u = 0; u < 8; u++) xn[u] = xp[(size_t)(c0 + 8 + u) * HW];
    }
#pragma unroll
    for (int u = 0; u < 8; u++) {
      const float* kw = kwT + (cs * 128 + c0 + u) * 64 + ob;  // uniform -> s_load
#pragma unroll
      for (int o = 0; o < 25; o++) acc[o] += xc[u] * kw[o];
    }
#pragma unroll
    for (int u = 0; u < 8; u++) xc[u] = xn[u];
  }
  float* op = kpart + (((size_t)(cs * B + b) * KK) + ob) * HW + n;
#pragma unroll
  for (int o = 0; o < 25; o++) op[(size_t)o * HW] = acc[o];
}

// k2a: fused {sum 4 c-split partials + bias -> keyraw} + {row max, 1/sumexp}
__global__ __launch_bounds__(256) void k2a_fused(
    const float* __restrict__ kpart, const float* __restrict__ Kb,
    float* __restrict__ keyraw, float* __restrict__ stats) {
  int row = blockIdx.x;  // b*49+o
  const float* p = kpart + (size_t)row * HW;
  float* kout = keyraw + (size_t)row * HW;
  int tid = threadIdx.x;
  float bb = Kb[row % KK];
  float4 v[4];
  float mx = -1e30f;
#pragma unroll
  for (int j = 0; j < 4; j++) {
    int idx = tid + j * 256;
    float4 s = ((const float4*)p)[idx];
#pragma unroll
    for (int k = 1; k < 4; k++) {
      float4 t = ((const float4*)(p + (size_t)k * KP_SLICE))[idx];
      s.x += t.x; s.y += t.y; s.z += t.z; s.w += t.w;
    }
    s.x += bb; s.y += bb; s.z += bb; s.w += bb;
    ((float4*)kout)[idx] = s;
    v[j] = s;
    mx = fmaxf(mx, fmaxf(fmaxf(s.x, s.y), fmaxf(s.z, s.w)));
  }
  for (int s = 32; s > 0; s >>= 1) mx = fmaxf(mx, __shfl_xor(mx, s));
  __shared__ float red[8];
  int wv = tid >> 6, ln = tid & 63;
  if (ln == 0) red[wv] = mx;
  __syncthreads();
  mx = fmaxf(fmaxf(red[0], red[1]), fmaxf(red[2], red[3]));
  float sm = 0.f;
#pragma unroll
  for (int j = 0; j < 4; j++)
    sm += expf(v[j].x - mx) + expf(v[j].y - mx) + expf(v[j].z - mx) +
          expf(v[j].w - mx);
  for (int s = 32; s > 0; s >>= 1) sm += __shfl_xor(sm, s);
  __syncthreads();
  if (ln == 0) red[4 + wv] = sm;
  __syncthreads();
  if (tid == 0) {
    float s4 = red[4] + red[5] + red[6] + red[7];
    stats[row * 2] = mx;
    stats[row * 2 + 1] = 1.f / s4;
  }
}

// k2b: write softmaxed key TRANSPOSED: ksmT[b][n][o] (row padded to 64, zeros past 49)
__global__ __launch_bounds__(256) void k2b_write(
    const float* __restrict__ keyraw, const float* __restrict__ stats,
    float* __restrict__ ksmT) {
  int b = blockIdx.y;
  int n0 = blockIdx.x * 256;
  int tid = threadIdx.x;
  __shared__ float t[KK][257];
  for (int o = 0; o < KK; o++) {
    float mx = stats[(b * KK + o) * 2];
    float ri = stats[(b * KK + o) * 2 + 1];
    float v = keyraw[(size_t)(b * KK + o) * HW + n0 + tid];
    t[o][tid] = expf(v - mx) * ri;
  }
  __syncthreads();
  for (int i = tid; i < 4096; i += 256) {  // 256 rows x 16 float4
    int nl = i >> 4, o4 = (i & 15) * 4;
    float4 w;
    w.x = (o4 < KK) ? t[o4][nl] : 0.f;
    w.y = (o4 + 1 < KK) ? t[o4 + 1][nl] : 0.f;
    w.z = (o4 + 2 < KK) ? t[o4 + 2][nl] : 0.f;
    w.w = (o4 + 3 < KK) ? t[o4 + 3][nl] : 0.f;
    ((float4*)(ksmT + (size_t)(b * HW + n0 + nl) * 64))[i & 15] = w;
  }
}

// k3: fpart[ks][b][c][o] = sum_{n in ks-range(128)} x[b][c][n] * ksmT[b][n][o]
// o-split 2 (acc[25]) + 16-row LDS tile (16.7KB) -> 8 blocks/CU, full unroll
__global__ __launch_bounds__(256, 8) void k3_filters(
    const float* __restrict__ x, const float* __restrict__ ksmT,
    float* __restrict__ fpart) {
  int ct = blockIdx.x >> 1;        // 0..1 (c-tile of 256)
  int ob = (blockIdx.x & 1) * 24;  // o-half
  int ks = blockIdx.y;             // 0..31 (n-split, 128 each)
  int b = blockIdx.z;
  int tid = threadIdx.x;
  int c0 = ct * 256;
  int nbase = ks * 128;
  // stride 261 (%32=5): staging writes <=2 lanes/bank (free); reads 2-way (free)
  __shared__ float xT[16][261];
  float acc[25];
#pragma unroll
  for (int o = 0; o < 25; o++) acc[o] = 0.f;
  for (int n0 = nbase; n0 < nbase + 128; n0 += 16) {
#pragma unroll
    for (int k = 0; k < 4; k++) {
      int i = tid + k * 256;  // 1024 float4 slots: 256c x 4(n/4)
      int cl = i >> 2, nq = i & 3;
      float4 v = *(const float4*)(x + (size_t)(b * C + c0 + cl) * HW + n0 + nq * 4);
      xT[nq * 4 + 0][cl] = v.x;
      xT[nq * 4 + 1][cl] = v.y;
      xT[nq * 4 + 2][cl] = v.z;
      xT[nq * 4 + 3][cl] = v.w;
    }
    __syncthreads();
#pragma unroll
    for (int nn = 0; nn < 16; nn++) {
      float xv = xT[nn][tid];
      const float* kp = ksmT + (size_t)(b * HW + n0 + nn) * 64 + ob;  // s_load
#pragma unroll
      for (int o = 0; o < 25; o++) acc[o] += xv * kp[o];
    }
    __syncthreads();
  }
  float* outp = fpart + ((size_t)(ks * B + b) * C + c0 + tid) * KK + ob;
#pragma unroll
  for (int o = 0; o < 25; o++) outp[o] = acc[o];
}

// k3s: fsum = sum over 32 n-split partials
__global__ __launch_bounds__(256) void k3_sum(
    const float* __restrict__ fpart, float* __restrict__ fsum) {
  int i = blockIdx.x * 256 + threadIdx.x;  // float4 slot, 100352 total
  const int stride = B * C * KK / 4;
  float4 s = ((const float4*)fpart)[i];
#pragma unroll
  for (int k = 1; k < 32; k++) {
    float4 v = ((const float4*)fpart)[i + k * stride];
    s.x += v.x; s.y += v.y; s.z += v.z; s.w += v.w;
  }
  ((float4*)fsum)[i] = s;
}

// k4_gemm: out[b][o][ij] = sum_c wT[c][o] * fin[b][c][ij] + bias[o]
__global__ __launch_bounds__(256) void k4_gemm(
    const float* __restrict__ fin, const float* __restrict__ wT,
    const float* __restrict__ bias, float* __restrict__ outp) {
  int og = blockIdx.x;  // 0..31
  int b = blockIdx.y;
  int tid = threadIdx.x, wv = tid >> 6, ln = tid & 63;
  bool act = ln < KK;
  float acc[16];
#pragma unroll
  for (int k = 0; k < 16; k++) acc[k] = 0.f;
  for (int c = wv * 128; c < wv * 128 + 128; c++) {
    float f = act ? fin[(size_t)(b * C + c) * KK + ln] : 0.f;
    const float* w = wT + (size_t)c * C + og * 16;
#pragma unroll
    for (int k = 0; k < 16; k++) acc[k] += f * w[k];
  }
  __shared__ float red[4][64][17];
#pragma unroll
  for (int k = 0; k < 16; k++) red[wv][ln][k] = acc[k];
  __syncthreads();
  if (wv == 0 && act) {
#pragma unroll
    for (int k = 0; k < 16; k++) {
      float s = red[0][ln][k] + red[1][ln][k] + red[2][ln][k] + red[3][ln][k] +
                bias[og * 16 + k];
      outp[(size_t)(b * C + og * 16 + k) * KK + ln] = s;
    }
  }
}

// k4_ln: per-b LayerNorm over 25088 elems + relu -> g
__global__ __launch_bounds__(256) void k4_ln(
    const float* __restrict__ t0, const float* __restrict__ lnw,
    const float* __restrict__ lnb, float* __restrict__ g) {
  int b = blockIdx.x, tid = threadIdx.x;
  const int NE = C * KK;  // 25088
  const float* p = t0 + (size_t)b * NE;
  float s = 0.f, q = 0.f;
  for (int i = tid; i < NE / 4; i += 256) {
    float4 v = ((const float4*)p)[i];
    s += v.x + v.y + v.z + v.w;
    q += v.x * v.x + v.y * v.y + v.z * v.z + v.w * v.w;
  }
  for (int sh = 32; sh > 0; sh >>= 1) {
    s += __shfl_xor(s, sh);
    q += __shfl_xor(q, sh);
  }
  __shared__ float rs[4], rq[4];
  int wv = tid >> 6, ln = tid & 63;
  if (ln == 0) { rs[wv] = s; rq[wv] = q; }
  __syncthreads();
  s = rs[0] + rs[1] + rs[2] + rs[3];
  q = rq[0] + rq[1] + rq[2] + rq[3];
  float mean = s / NE;
  float var = q / NE - mean * mean;
  float rstd = rsqrtf(var + 1e-5f);
  float* go = g + (size_t)b * NE;
  for (int i = tid; i < NE; i += 256) {
    float v = (p[i] - mean) * rstd * lnw[i] + lnb[i];
    go[i] = fmaxf(v, 0.f);
  }
}

// k5: depthwise 7x7, zero-pad 3; one block per (c,b) plane; 4x4 reg tile/thread
__global__ __launch_bounds__(256) void k5_dwconv(
    const float* __restrict__ x, const float* __restrict__ filt,
    float* __restrict__ outp) {
  int c = blockIdx.x, b = blockIdx.y, tid = threadIdx.x;
  __shared__ float xs[70][76];
  for (int i = tid; i < 70 * 19; i += 256)
    ((float4*)&xs[0][0])[i] = make_float4(0.f, 0.f, 0.f, 0.f);
  __syncthreads();
  const float* xp = x + (size_t)(b * C + c) * HW;
  for (int i = tid; i < 1024; i += 256) {
    int r = i >> 4, c4 = (i & 15) * 4;
    float4 v = ((const float4*)(xp + r * 64))[i & 15];
    xs[3 + r][3 + c4 + 0] = v.x;
    xs[3 + r][3 + c4 + 1] = v.y;
    xs[3 + r][3 + c4 + 2] = v.z;
    xs[3 + r][3 + c4 + 3] = v.w;
  }
  const float* fp = filt + (size_t)(b * C + c) * KK;
  float f[KK];
#pragma unroll
  for (int k = 0; k < KK; k++) f[k] = fp[k];
  __syncthreads();
  int tr = (tid >> 4) * 4, tc = (tid & 15) * 4;
  float acc[4][4];
#pragma unroll
  for (int r = 0; r < 4; r++)
#pragma unroll
    for (int j = 0; j < 4; j++) acc[r][j] = 0.f;
#pragma unroll
  for (int ii = 0; ii < 10; ii++) {
    float v[12];
#pragma unroll
    for (int q = 0; q < 3; q++) {
      float4 t4 = *(const float4*)&xs[tr + ii][tc + q * 4];
      v[q * 4 + 0] = t4.x; v[q * 4 + 1] = t4.y;
      v[q * 4 + 2] = t4.z; v[q * 4 + 3] = t4.w;
    }
#pragma unroll
    for (int rr = 0; rr < 4; rr++) {
      int kr = ii - rr;
      if (kr >= 0 && kr < 7) {
#pragma unroll
        for (int jj = 0; jj < 4; jj++)
#pragma unroll
          for (int kc = 0; kc < 7; kc++)
            acc[rr][jj] += f[kr * 7 + kc] * v[jj + kc];
      }
    }
  }
  float* op = outp + (size_t)(b * C + c) * HW;
#pragma unroll
  for (int rr = 0; rr < 4; rr++) {
    float4 w = make_float4(acc[rr][0], acc[rr][1], acc[rr][2], acc[rr][3]);
    *(float4*)(op + (tr + rr) * 64 + tc) = w;
  }
}

extern "C" void kernel_launch(void* const* d_in, const int* in_sizes, int n_in,
                              void* d_out, int out_size, void* d_ws,
                              size_t ws_size, hipStream_t stream) {
  const float* x   = (const float*)d_in[0];
  const float* K_w = (const float*)d_in[1];
  const float* K_b = (const float*)d_in[2];
  const float* c0w = (const float*)d_in[3];
  const float* c0b = (const float*)d_in[4];
  const float* lnw = (const float*)d_in[5];
  const float* lnb = (const float*)d_in[6];
  const float* c1w = (const float*)d_in[7];
  const float* c1b = (const float*)d_in[8];
  float* outp = (float*)d_out;
  float* ws = (float*)d_ws;

  float* kwT    = ws + OFF_KWT;
  float* c0wT   = ws + OFF_C0WT;
  float* c1wT   = ws + OFF_C1WT;
  float* stats  = ws + OFF_STATS;
  float* keyraw = ws + OFF_KEYRAW;
  float* fsum   = ws + OFF_FSUM;
  float* t0     = ws + OFF_T0;
  float* g      = ws + OFF_G;
  float* t1     = ws + OFF_T1;
  float* ksmT   = ws + OFF_KSMT;
  float* kpart  = ws + OFF_KPART;
  float* fpart  = ws + OFF_FPART;

  k0_transpose<<<1024, 256, 0, stream>>>(K_w, c0w, c1w, kwT, c0wT, c1wT);
  k1_key<<<dim3(16, 16, 8), 256, 0, stream>>>(x, kwT, kpart);
  k2a_fused<<<B * KK, 256, 0, stream>>>(kpart, K_b, keyraw, stats);
  k2b_write<<<dim3(16, 16), 256, 0, stream>>>(keyraw, stats, ksmT);
  k3_filters<<<dim3(4, 32, 16), 256, 0, stream>>>(x, ksmT, fpart);
  k3_sum<<<392, 256, 0, stream>>>(fpart, fsum);
  k4_gemm<<<dim3(32, 16), 256, 0, stream>>>(fsum, c0wT, c0b, t0);
  k4_ln<<<16, 256, 0, stream>>>(t0, lnw, lnb, g);
  k4_gemm<<<dim3(32, 16), 256, 0, stream>>>(g, c1wT, c1b, t1);
  k5_dwconv<<<dim3(C, B), 256, 0, stream>>>(x, t1, outp);
}

// Round 6
// 487.395 us; speedup vs baseline: 1.1981x; 1.1981x over previous
//
#include <hip/hip_runtime.h>
#include <hip/hip_bf16.h>

#define B 16
#define C 512
#define HW 4096
#define KK 49

typedef __bf16 bf16x8 __attribute__((ext_vector_type(8)));
typedef float f32x4 __attribute__((ext_vector_type(4)));
typedef unsigned int uint4v __attribute__((ext_vector_type(4)));
typedef unsigned short ushort;

__device__ inline ushort f2b(float f) {
  __hip_bfloat16 h = __float2bfloat16(f);
  return __builtin_bit_cast(ushort, h);
}
__device__ inline float b2f(ushort u) {
  __hip_bfloat16 h = __builtin_bit_cast(__hip_bfloat16, u);
  return __bfloat162float(h);
}
__device__ inline unsigned int pk2(float a, float b) {
  return (unsigned int)f2b(a) | ((unsigned int)f2b(b) << 16);
}

// ---------------- workspace layout (float offsets) ----------------
// kwB   ushort[64g][64o][8j]           @0        (16384 f)
// c0wT  f32[512][512]                  @16384
// c1wT  f32[512][512]                  @278528
// stats f32[B][64][2]                  @540672   (2048)
// pstat f32[B][64][8][2]               @542720   (16384)
// keyTb ushort[B][4096][64]            @559104   (2097152 f) dead after k2c
// fsum  f32[B][512][49]                @2656256
// t0    f32[B][512][49]                @3057664
// g     f32[B][512][49]                @3459072
// t1    f32[B][512][49]                @3860480  end 4261888
// ksmB  ushort[B][512gn][64o][8j]      @4745216  (2097152 f)
// xA    ushort[B][512gn][512c][8j]     @6842368  (16777216 f)
// xB    ushort[B][64g][4096n][8j]      @23619584 (16777216 f) dead after k1
//   fpart f32[8][B][512][64]           @23619584 OVERLAY     (4194304 f)
// total 40,396,800 floats = 161.6 MB
#define OFF_KWB    0
#define OFF_C0WT   16384
#define OFF_C1WT   278528
#define OFF_STATS  540672
#define OFF_PSTAT  542720
#define OFF_KEYTB  559104
#define OFF_FSUM   2656256
#define OFF_T0     3057664
#define OFF_G      3459072
#define OFF_T1     3860480
#define OFF_KSMB   4745216
#define OFF_XA     6842368
#define OFF_XB     23619584
#define OFF_FPART  23619584

// k0: pack K_w -> kwB bf16 B-fragment layout (zero o>=49); transpose conv weights
__global__ __launch_bounds__(256) void k0_prep(
    const float* __restrict__ K_w, const float* __restrict__ c0w,
    const float* __restrict__ c1w, ushort* __restrict__ kwB,
    float* __restrict__ c0wT, float* __restrict__ c1wT) {
  int i = blockIdx.x * 256 + threadIdx.x;
  if (i < 32768) {  // i = g*512 + o*8 + j
    int g = i >> 9, o = (i >> 3) & 63, j = i & 7;
    kwB[i] = (o < KK) ? f2b(K_w[o * 512 + g * 8 + j]) : (ushort)0;
  }
  if (i < 512 * 512) {
    int cc = i >> 9, oo = i & 511;
    c0wT[i] = c0w[oo * 512 + cc];
    c1wT[i] = c1w[oo * 512 + cc];
  }
}

// kcvt: x fp32 -> xA (n-grouped) and xB (c-grouped) bf16 fragment layouts
__global__ __launch_bounds__(256) void kcvt(
    const float* __restrict__ x, ushort* __restrict__ xA,
    ushort* __restrict__ xB) {
  int nt = blockIdx.x, ct = blockIdx.y, b = blockIdx.z;
  int cb = ct * 64, nb = nt * 64;
  int t = threadIdx.x;
  __shared__ float xs[64][65];
#pragma unroll
  for (int ii = 0; ii < 4; ii++) {
    int task = t + ii * 256;  // 64 rows x 16 float4
    int row = task >> 4, q = task & 15;
    float4 v = *(const float4*)(x + (size_t)(b * C + cb + row) * HW + nb + q * 4);
    xs[row][q * 4 + 0] = v.x;
    xs[row][q * 4 + 1] = v.y;
    xs[row][q * 4 + 2] = v.z;
    xs[row][q * 4 + 3] = v.w;
  }
  __syncthreads();
  uint4v* xA4 = (uint4v*)xA;
  uint4v* xB4 = (uint4v*)xB;
#pragma unroll
  for (int ii = 0; ii < 2; ii++) {
    int u = t + ii * 256;
    {  // xA: chunk (b, gn, c), elems j = n&7
      int c = u & 63, gnl = u >> 6;
      float f0 = xs[c][gnl * 8 + 0], f1 = xs[c][gnl * 8 + 1];
      float f2 = xs[c][gnl * 8 + 2], f3 = xs[c][gnl * 8 + 3];
      float f4 = xs[c][gnl * 8 + 4], f5 = xs[c][gnl * 8 + 5];
      float f6 = xs[c][gnl * 8 + 6], f7 = xs[c][gnl * 8 + 7];
      uint4v w;
      w[0] = pk2(f0, f1); w[1] = pk2(f2, f3);
      w[2] = pk2(f4, f5); w[3] = pk2(f6, f7);
      xA4[(size_t)(b * 512 + (nb >> 3) + gnl) * 512 + cb + c] = w;
    }
    {  // xB: chunk (b, g=c/8, n), elems j = c&7
      int n = u & 63, gl = u >> 6;
      float f0 = xs[gl * 8 + 0][n], f1 = xs[gl * 8 + 1][n];
      float f2 = xs[gl * 8 + 2][n], f3 = xs[gl * 8 + 3][n];
      float f4 = xs[gl * 8 + 4][n], f5 = xs[gl * 8 + 5][n];
      float f6 = xs[gl * 8 + 6][n], f7 = xs[gl * 8 + 7][n];
      uint4v w;
      w[0] = pk2(f0, f1); w[1] = pk2(f2, f3);
      w[2] = pk2(f4, f5); w[3] = pk2(f6, f7);
      xB4[(size_t)(b * 64 + (cb >> 3) + gl) * 4096 + nb + n] = w;
    }
  }
}

// k1: keyT[b][n][o64] = sum_c x[b][c][n]*K_w[o][c]  (MFMA, output bf16)
__global__ __launch_bounds__(256) void k1_mfma(
    const ushort* __restrict__ xB, const ushort* __restrict__ kwB,
    ushort* __restrict__ keyTb) {
  int nt = blockIdx.x, b = blockIdx.y;
  int nb = nt * 64;
  int t = threadIdx.x, wv = t >> 6, l = t & 63;
  const uint4v* xB4 = (const uint4v*)xB;
  const uint4v* kw4 = (const uint4v*)kwB;
  f32x4 acc[4];
#pragma unroll
  for (int ot = 0; ot < 4; ot++) acc[ot] = (f32x4)(0.f);
  int lrow = l & 15, lk = l >> 4;
#pragma unroll
  for (int ks = 0; ks < 16; ks++) {
    bf16x8 a = __builtin_bit_cast(bf16x8,
        xB4[(size_t)(b * 64 + ks * 4 + lk) * 4096 + nb + wv * 16 + lrow]);
#pragma unroll
    for (int ot = 0; ot < 4; ot++) {
      bf16x8 bf = __builtin_bit_cast(bf16x8,
          kw4[(ks * 4 + lk) * 64 + ot * 16 + lrow]);
      acc[ot] = __builtin_amdgcn_mfma_f32_16x16x32_bf16(a, bf, acc[ot], 0, 0, 0);
    }
  }
#pragma unroll
  for (int ot = 0; ot < 4; ot++) {
#pragma unroll
    for (int r = 0; r < 4; r++) {
      int n = nb + wv * 16 + lk * 4 + r;
      int o = ot * 16 + lrow;
      keyTb[(size_t)(b * HW + n) * 64 + o] = f2b(acc[ot][r]);
    }
  }
}

// k2p: per (b, og, nc) partial online softmax over n for 16 o-columns
__global__ __launch_bounds__(256) void k2p(
    const ushort* __restrict__ keyTb, float* __restrict__ pstat) {
  int og = blockIdx.x, nc = blockIdx.y, b = blockIdx.z;
  int t = threadIdx.x;
  int o = og * 16 + (t & 15);
  int nl = t >> 4;
  float m = -3.0e38f, s = 0.f;
  for (int it = 0; it < 32; it++) {
    int n = nc * 512 + nl + 16 * it;
    float v = b2f(keyTb[(size_t)(b * HW + n) * 64 + o]);
    float m2 = fmaxf(m, v);
    s = s * __expf(m - m2) + __expf(v - m2);
    m = m2;
  }
#pragma unroll
  for (int sh = 16; sh <= 32; sh <<= 1) {
    float m2 = __shfl_xor(m, sh), s2 = __shfl_xor(s, sh);
    float M = fmaxf(m, m2);
    s = s * __expf(m - M) + s2 * __expf(m2 - M);
    m = M;
  }
  __shared__ float rm[4][16], rs[4][16];
  int wv = t >> 6, l = t & 63;
  if (l < 16) { rm[wv][l] = m; rs[wv][l] = s; }
  __syncthreads();
  if (t < 16) {
    float M = rm[0][t], S = rs[0][t];
#pragma unroll
    for (int w = 1; w < 4; w++) {
      float m2 = rm[w][t], s2 = rs[w][t];
      float Mn = fmaxf(M, m2);
      S = S * __expf(M - Mn) + s2 * __expf(m2 - Mn);
      M = Mn;
    }
    int oo = og * 16 + t;
    pstat[((b * 64 + oo) * 8 + nc) * 2] = M;
    pstat[((b * 64 + oo) * 8 + nc) * 2 + 1] = S;
  }
}

// k2s: combine 8 partials -> stats {max, 1/sum}; zero for o>=49
__global__ __launch_bounds__(256) void k2s(
    const float* __restrict__ pstat, float* __restrict__ stats) {
  int id = blockIdx.x * 256 + threadIdx.x;
  if (id >= B * 64) return;
  int b = id >> 6, o = id & 63;
  float M = -3.0e38f, S = 0.f;
#pragma unroll
  for (int k = 0; k < 8; k++) {
    float m2 = pstat[((b * 64 + o) * 8 + k) * 2];
    float s2 = pstat[((b * 64 + o) * 8 + k) * 2 + 1];
    float Mn = fmaxf(M, m2);
    S = S * __expf(M - Mn) + s2 * __expf(m2 - Mn);
    M = Mn;
  }
  stats[(b * 64 + o) * 2] = (o < KK) ? M : 0.f;
  stats[(b * 64 + o) * 2 + 1] = (o < KK) ? 1.f / S : 0.f;
}

// k2c: ksmB[b][gn][o][j=n&7] = bf16(softmax) in B-fragment layout
__global__ __launch_bounds__(256) void k2c(
    const ushort* __restrict__ keyTb, const float* __restrict__ stats,
    ushort* __restrict__ ksmB) {
  int nch = blockIdx.x, b = blockIdx.y;
  int gnb = nch * 16;
  int t = threadIdx.x;
  uint4v* ks4 = (uint4v*)ksmB;
#pragma unroll
  for (int ii = 0; ii < 4; ii++) {
    int u = t + ii * 256;
    int o = u & 63, gn = gnb + (u >> 6);
    float mx = stats[(b * 64 + o) * 2];
    float ri = stats[(b * 64 + o) * 2 + 1];
    float w[8];
#pragma unroll
    for (int j = 0; j < 8; j++) {
      float v = b2f(keyTb[(size_t)(b * HW + gn * 8 + j) * 64 + o]);
      w[j] = __expf(v - mx) * ri;
    }
    uint4v pw;
    pw[0] = pk2(w[0], w[1]); pw[1] = pk2(w[2], w[3]);
    pw[2] = pk2(w[4], w[5]); pw[3] = pk2(w[6], w[7]);
    ks4[(size_t)(b * 512 + gn) * 64 + o] = pw;
  }
}

// k3: fpart[ks][b][c][o64] = sum_{n chunk} x[b][c][n]*ksm[b][n][o]  (MFMA)
__global__ __launch_bounds__(256) void k3_mfma(
    const ushort* __restrict__ xA, const ushort* __restrict__ ksmB,
    float* __restrict__ fpart) {
  int ct = blockIdx.x, ksi = blockIdx.y, b = blockIdx.z;
  int cb = ct * 64;
  int t = threadIdx.x, wv = t >> 6, l = t & 63;
  const uint4v* xA4 = (const uint4v*)xA;
  const uint4v* ks4 = (const uint4v*)ksmB;
  f32x4 acc[4];
#pragma unroll
  for (int ot = 0; ot < 4; ot++) acc[ot] = (f32x4)(0.f);
  int lrow = l & 15, lk = l >> 4;
#pragma unroll
  for (int ks = 0; ks < 16; ks++) {
    int gbase = ksi * 64 + ks * 4 + lk;
    bf16x8 a = __builtin_bit_cast(bf16x8,
        xA4[(size_t)(b * 512 + gbase) * 512 + cb + wv * 16 + lrow]);
#pragma unroll
    for (int ot = 0; ot < 4; ot++) {
      bf16x8 bf = __builtin_bit_cast(bf16x8,
          ks4[(size_t)(b * 512 + gbase) * 64 + ot * 16 + lrow]);
      acc[ot] = __builtin_amdgcn_mfma_f32_16x16x32_bf16(a, bf, acc[ot], 0, 0, 0);
    }
  }
#pragma unroll
  for (int ot = 0; ot < 4; ot++) {
#pragma unroll
    for (int r = 0; r < 4; r++) {
      int c = cb + wv * 16 + lk * 4 + r;
      int o = ot * 16 + lrow;
      fpart[((size_t)(ksi * B + b) * 512 + c) * 64 + o] = acc[ot][r];
    }
  }
}

// k3s: fsum[b][c][49] = sum over 8 K-chunks (drop o>=49)
__global__ __launch_bounds__(256) void k3s(
    const float* __restrict__ fpart, float* __restrict__ fsum) {
  int id = blockIdx.x * 256 + threadIdx.x;  // over B*512*64
  int o = id & 63, c = (id >> 6) & 511, b = id >> 15;
  if (o >= KK) return;
  float s = 0.f;
#pragma unroll
  for (int k = 0; k < 8; k++)
    s += fpart[((size_t)(k * B + b) * 512 + c) * 64 + o];
  fsum[(size_t)(b * 512 + c) * KK + o] = s;
}

// k4_gemm: out[b][o][ij] = sum_c wT[c][o] * fin[b][c][ij] + bias[o]
__global__ __launch_bounds__(256) void k4_gemm(
    const float* __restrict__ fin, const float* __restrict__ wT,
    const float* __restrict__ bias, float* __restrict__ outp) {
  int og = blockIdx.x;
  int b = blockIdx.y;
  int tid = threadIdx.x, wv = tid >> 6, ln = tid & 63;
  bool act = ln < KK;
  float acc[16];
#pragma unroll
  for (int k = 0; k < 16; k++) acc[k] = 0.f;
  for (int c = wv * 128; c < wv * 128 + 128; c++) {
    float f = act ? fin[(size_t)(b * C + c) * KK + ln] : 0.f;
    const float* w = wT + (size_t)c * C + og * 16;
#pragma unroll
    for (int k = 0; k < 16; k++) acc[k] += f * w[k];
  }
  __shared__ float red[4][64][17];
#pragma unroll
  for (int k = 0; k < 16; k++) red[wv][ln][k] = acc[k];
  __syncthreads();
  if (wv == 0 && act) {
#pragma unroll
    for (int k = 0; k < 16; k++) {
      float s = red[0][ln][k] + red[1][ln][k] + red[2][ln][k] + red[3][ln][k] +
                bias[og * 16 + k];
      outp[(size_t)(b * C + og * 16 + k) * KK + ln] = s;
    }
  }
}

// k4_ln: per-b LayerNorm over 25088 elems + relu -> g
__global__ __launch_bounds__(256) void k4_ln(
    const float* __restrict__ t0, const float* __restrict__ lnw,
    const float* __restrict__ lnb, float* __restrict__ g) {
  int b = blockIdx.x, tid = threadIdx.x;
  const int NE = C * KK;
  const float* p = t0 + (size_t)b * NE;
  float s = 0.f, q = 0.f;
  for (int i = tid; i < NE / 4; i += 256) {
    float4 v = ((const float4*)p)[i];
    s += v.x + v.y + v.z + v.w;
    q += v.x * v.x + v.y * v.y + v.z * v.z + v.w * v.w;
  }
  for (int sh = 32; sh > 0; sh >>= 1) {
    s += __shfl_xor(s, sh);
    q += __shfl_xor(q, sh);
  }
  __shared__ float rs[4], rq[4];
  int wv = tid >> 6, ln = tid & 63;
  if (ln == 0) { rs[wv] = s; rq[wv] = q; }
  __syncthreads();
  s = rs[0] + rs[1] + rs[2] + rs[3];
  q = rq[0] + rq[1] + rq[2] + rq[3];
  float mean = s / NE;
  float var = q / NE - mean * mean;
  float rstd = rsqrtf(var + 1e-5f);
  float* go = g + (size_t)b * NE;
  for (int i = tid; i < NE; i += 256) {
    float v = (p[i] - mean) * rstd * lnw[i] + lnb[i];
    go[i] = fmaxf(v, 0.f);
  }
}

// k5: depthwise 7x7, zero-pad 3; one block per (c,b) plane
__global__ __launch_bounds__(256) void k5_dwconv(
    const float* __restrict__ x, const float* __restrict__ filt,
    float* __restrict__ outp) {
  int c = blockIdx.x, b = blockIdx.y, tid = threadIdx.x;
  __shared__ float xs[70][76];
  for (int i = tid; i < 70 * 19; i += 256)
    ((float4*)&xs[0][0])[i] = make_float4(0.f, 0.f, 0.f, 0.f);
  __syncthreads();
  const float* xp = x + (size_t)(b * C + c) * HW;
  for (int i = tid; i < 1024; i += 256) {
    int r = i >> 4, c4 = (i & 15) * 4;
    float4 v = ((const float4*)(xp + r * 64))[i & 15];
    xs[3 + r][3 + c4 + 0] = v.x;
    xs[3 + r][3 + c4 + 1] = v.y;
    xs[3 + r][3 + c4 + 2] = v.z;
    xs[3 + r][3 + c4 + 3] = v.w;
  }
  const float* fp = filt + (size_t)(b * C + c) * KK;
  float f[KK];
#pragma unroll
  for (int k = 0; k < KK; k++) f[k] = fp[k];
  __syncthreads();
  int tr = (tid >> 4) * 4, tc = (tid & 15) * 4;
  float acc[4][4];
#pragma unroll
  for (int r = 0; r < 4; r++)
#pragma unroll
    for (int j = 0; j < 4; j++) acc[r][j] = 0.f;
#pragma unroll
  for (int ii = 0; ii < 10; ii++) {
    float v[12];
#pragma unroll
    for (int q = 0; q < 3; q++) {
      float4 t4 = *(const float4*)&xs[tr + ii][tc + q * 4];
      v[q * 4 + 0] = t4.x; v[q * 4 + 1] = t4.y;
      v[q * 4 + 2] = t4.z; v[q * 4 + 3] = t4.w;
    }
#pragma unroll
    for (int rr = 0; rr < 4; rr++) {
      int kr = ii - rr;
      if (kr >= 0 && kr < 7) {
#pragma unroll
        for (int jj = 0; jj < 4; jj++)
#pragma unroll
          for (int kc = 0; kc < 7; kc++)
            acc[rr][jj] += f[kr * 7 + kc] * v[jj + kc];
      }
    }
  }
  float* op = outp + (size_t)(b * C + c) * HW;
#pragma unroll
  for (int rr = 0; rr < 4; rr++) {
    float4 w = make_float4(acc[rr][0], acc[rr][1], acc[rr][2], acc[rr][3]);
    *(float4*)(op + (tr + rr) * 64 + tc) = w;
  }
}

extern "C" void kernel_launch(void* const* d_in, const int* in_sizes, int n_in,
                              void* d_out, int out_size, void* d_ws,
                              size_t ws_size, hipStream_t stream) {
  const float* x   = (const float*)d_in[0];
  const float* K_w = (const float*)d_in[1];
  // K_b = d_in[2] is all-zeros in setup; softmax is shift-invariant per-o anyway
  const float* c0w = (const float*)d_in[3];
  const float* c0b = (const float*)d_in[4];
  const float* lnw = (const float*)d_in[5];
  const float* lnb = (const float*)d_in[6];
  const float* c1w = (const float*)d_in[7];
  const float* c1b = (const float*)d_in[8];
  float* outp = (float*)d_out;
  float* ws = (float*)d_ws;

  ushort* kwB   = (ushort*)(ws + OFF_KWB);
  float*  c0wT  = ws + OFF_C0WT;
  float*  c1wT  = ws + OFF_C1WT;
  float*  stats = ws + OFF_STATS;
  float*  pstat = ws + OFF_PSTAT;
  ushort* keyTb = (ushort*)(ws + OFF_KEYTB);
  float*  fsum  = ws + OFF_FSUM;
  float*  t0    = ws + OFF_T0;
  float*  g     = ws + OFF_G;
  float*  t1    = ws + OFF_T1;
  ushort* ksmB  = (ushort*)(ws + OFF_KSMB);
  ushort* xA    = (ushort*)(ws + OFF_XA);
  ushort* xB    = (ushort*)(ws + OFF_XB);
  float*  fpart = ws + OFF_FPART;

  k0_prep<<<1024, 256, 0, stream>>>(K_w, c0w, c1w, kwB, c0wT, c1wT);
  kcvt<<<dim3(64, 8, 16), 256, 0, stream>>>(x, xA, xB);
  k1_mfma<<<dim3(64, 16), 256, 0, stream>>>(xB, kwB, keyTb);
  k2p<<<dim3(4, 8, 16), 256, 0, stream>>>(keyTb, pstat);
  k2s<<<4, 256, 0, stream>>>(pstat, stats);
  k2c<<<dim3(32, 16), 256, 0, stream>>>(keyTb, stats, ksmB);
  k3_mfma<<<dim3(8, 8, 16), 256, 0, stream>>>(xA, ksmB, fpart);
  k3s<<<2048, 256, 0, stream>>>(fpart, fsum);
  k4_gemm<<<dim3(32, 16), 256, 0, stream>>>(fsum, c0wT, c0b, t0);
  k4_ln<<<16, 256, 0, stream>>>(t0, lnw, lnb, g);
  k4_gemm<<<dim3(32, 16), 256, 0, stream>>>(g, c1wT, c1b, t1);
  k5_dwconv<<<dim3(C, B), 256, 0, stream>>>(x, t1, outp);
}